// Round 1
// baseline (87.712 us; speedup 1.0000x reference)
//
#include <hip/hip_runtime.h>
#include <hip/hip_bf16.h>

typedef __bf16 bf16x8 __attribute__((ext_vector_type(8)));
typedef float  f32x4  __attribute__((ext_vector_type(4)));

#define UBV    35.0f
#define SUMC   150.0f
#define SLOPE  0.2f

// Geometry: B=65536, S=17, H1=400, H2=300, A=5
// Padded: K1=32 (17->32), N1=400 (25 tiles), K2=416 (13x32), N2=304 (19 tiles)
#define K1P 32
#define K2P 416
#define N2P 304
#define H1STRIDE 424   // 416 + 8 pad -> row offset 212 dwords (20 mod 32) => 2-way (free)

__device__ __forceinline__ float lrelu(float x) { return x > 0.f ? x : SLOPE * x; }

__global__ void prep_kernel(const float* __restrict__ W1,
                            const float* __restrict__ W2,
                            __bf16* __restrict__ w1bf,   // [400][32]
                            __bf16* __restrict__ w2bf)   // [304][416]
{
    int idx = blockIdx.x * blockDim.x + threadIdx.x;
    const int total1 = 400 * K1P;
    const int total2 = N2P * K2P;
    if (idx < total1) {
        int j = idx >> 5, k = idx & 31;
        w1bf[idx] = (k < 17) ? (__bf16)W1[j * 17 + k] : (__bf16)0.f;
    } else if (idx < total1 + total2) {
        int i2 = idx - total1;
        int n = i2 / K2P, k = i2 - n * K2P;
        w2bf[i2] = (n < 300 && k < 400) ? (__bf16)W2[n * 400 + k] : (__bf16)0.f;
    }
}

__global__ __launch_bounds__(256, 2)
void actor_kernel(const float* __restrict__ state,
                  const __bf16* __restrict__ w1bf,
                  const float* __restrict__ b1,
                  const __bf16* __restrict__ w2bf,
                  const float* __restrict__ b2,
                  const float* __restrict__ W3,
                  const float* __restrict__ b3,
                  float* __restrict__ out)
{
    __shared__ float  s_state[64][17];         // 4.4 KB
    __shared__ __bf16 s_h1[64][H1STRIDE];      // 54.3 KB
    __shared__ float  s_b1[400];
    __shared__ float  s_b2[N2P];
    __shared__ float  s_w3[5][N2P];            // 6.1 KB
    __shared__ float  s_b3[5];

    const int tid  = threadIdx.x;
    const int wave = tid >> 6;
    const int lane = tid & 63;
    const int g    = lane >> 4;     // k-group 0..3
    const int c16  = lane & 15;     // column / row-in-tile index
    const int brow = blockIdx.x * 64;
    const int mrow = wave * 16;     // this wave's 16-row tile within the block

    // ---- stage state tile + biases + W3; zero h1 pad cols 400..423 ----
    for (int i = tid; i < 64 * 17; i += 256) {
        int r = i / 17, c = i - r * 17;
        s_state[r][c] = state[(brow + r) * 17 + c];
    }
    for (int i = tid; i < 400; i += 256) s_b1[i] = b1[i];
    for (int i = tid; i < N2P; i += 256) s_b2[i] = (i < 300) ? b2[i] : 0.f;
    for (int i = tid; i < 5 * N2P; i += 256) {
        int o = i / N2P, c = i - o * N2P;
        s_w3[o][c] = (c < 300) ? W3[o * 300 + c] : 0.f;
    }
    if (tid < 5) s_b3[tid] = b3[tid];
    for (int i = tid; i < 64 * 24; i += 256) {
        int r = i / 24, c = 400 + (i - r * 24);
        s_h1[r][c] = (__bf16)0.f;
    }
    __syncthreads();

    // ---- Phase A: layer 1 via MFMA (h1 = lrelu(state @ W1^T + b1)) ----
    // A-frag: lane holds row (mrow + c16), k = g*8 + j (k>=17 -> 0)
    bf16x8 afrag;
    #pragma unroll
    for (int j = 0; j < 8; ++j) {
        int k = g * 8 + j;
        float x = (k < 17) ? s_state[mrow + c16][k] : 0.f;
        afrag[j] = (__bf16)x;
    }
    for (int nt = 0; nt < 25; ++nt) {
        const __bf16* bp_ = &w1bf[(nt * 16 + c16) * K1P + g * 8];
        bf16x8 bfrag = *reinterpret_cast<const bf16x8*>(bp_);
        f32x4 acc = {0.f, 0.f, 0.f, 0.f};
        acc = __builtin_amdgcn_mfma_f32_16x16x32_bf16(afrag, bfrag, acc, 0, 0, 0);
        // C layout: col = c16, row = g*4 + r
        int jcol = nt * 16 + c16;
        float bias = s_b1[jcol];
        #pragma unroll
        for (int r = 0; r < 4; ++r) {
            float x = lrelu(acc[r] + bias);
            s_h1[mrow + g * 4 + r][jcol] = (__bf16)x;
        }
    }
    __syncthreads();

    // ---- Phase B: layer 2 MFMA + fused layer 3 partials ----
    bf16x8 af[13];
    #pragma unroll
    for (int kt = 0; kt < 13; ++kt) {
        const __bf16* p = &s_h1[mrow + c16][kt * 32 + g * 8];
        af[kt] = *reinterpret_cast<const bf16x8*>(p);
    }

    float part[5][4];
    #pragma unroll
    for (int o = 0; o < 5; ++o)
        #pragma unroll
        for (int r = 0; r < 4; ++r) part[o][r] = 0.f;

    for (int nt = 0; nt < 19; ++nt) {
        const __bf16* wb = &w2bf[(nt * 16 + c16) * K2P + g * 8];
        f32x4 acc = {0.f, 0.f, 0.f, 0.f};
        #pragma unroll
        for (int kt = 0; kt < 13; ++kt) {
            bf16x8 bfrag = *reinterpret_cast<const bf16x8*>(wb + kt * 32);
            acc = __builtin_amdgcn_mfma_f32_16x16x32_bf16(af[kt], bfrag, acc, 0, 0, 0);
        }
        int cc = nt * 16 + c16;
        float bias = s_b2[cc];
        float w3v[5];
        #pragma unroll
        for (int o = 0; o < 5; ++o) w3v[o] = s_w3[o][cc];
        #pragma unroll
        for (int r = 0; r < 4; ++r) {
            float h2 = lrelu(acc[r] + bias);
            #pragma unroll
            for (int o = 0; o < 5; ++o) part[o][r] += h2 * w3v[o];
        }
    }

    // ---- reduce across the 16 lanes sharing g (sum over columns) ----
    #pragma unroll
    for (int o = 0; o < 5; ++o)
        #pragma unroll
        for (int r = 0; r < 4; ++r) {
            float x = part[o][r];
            x += __shfl_xor(x, 1);
            x += __shfl_xor(x, 2);
            x += __shfl_xor(x, 4);
            x += __shfl_xor(x, 8);
            part[o][r] = x;
        }

    // ---- Phase C: QP projection (one lane per row: lanes with c16 < 4) ----
    if (c16 < 4) {
        float v[5];
        #pragma unroll
        for (int o = 0; o < 5; ++o) {
            float x = (c16 == 0) ? part[o][0] :
                      (c16 == 1) ? part[o][1] :
                      (c16 == 2) ? part[o][2] : part[o][3];
            x = lrelu(x + s_b3[o]);
            v[o] = -x;                       // QP linear term p = scaled_a, v = -p
        }
        // exact solve of sum(clip(v - nu, 0, UB)) = SUM via breakpoints
        float bp[10];
        #pragma unroll
        for (int i = 0; i < 5; ++i) { bp[i] = v[i]; bp[i + 5] = v[i] - UBV; }
        float blo = -1e30f, glo = 0.f;
        #pragma unroll
        for (int j = 0; j < 10; ++j) {
            float b = bp[j];
            float gsum = 0.f;
            #pragma unroll
            for (int i = 0; i < 5; ++i) {
                float z = v[i] - b;
                z = fminf(fmaxf(z, 0.f), UBV);
                gsum += z;
            }
            if (gsum >= SUMC && b > blo) { blo = b; glo = gsum; }
        }
        float bhi = 1e30f;
        #pragma unroll
        for (int j = 0; j < 10; ++j) {
            float b = bp[j];
            if (b > blo && b < bhi) bhi = b;
        }
        float mid = 0.5f * (blo + bhi);
        int nfree = 0;
        #pragma unroll
        for (int i = 0; i < 5; ++i)
            nfree += (v[i] > mid && v[i] < mid + UBV) ? 1 : 0;
        float nu = (nfree > 0) ? blo + (glo - SUMC) / (float)nfree : blo;

        int row = brow + mrow + g * 4 + c16;
        #pragma unroll
        for (int o = 0; o < 5; ++o) {
            float z = v[o] - nu;
            z = fminf(fmaxf(z, 0.f), UBV);
            out[row * 5 + o] = z;
        }
    }
}

extern "C" void kernel_launch(void* const* d_in, const int* in_sizes, int n_in,
                              void* d_out, int out_size, void* d_ws, size_t ws_size,
                              hipStream_t stream) {
    const float* state = (const float*)d_in[0];
    const float* W1    = (const float*)d_in[1];
    const float* b1    = (const float*)d_in[2];
    const float* W2    = (const float*)d_in[3];
    const float* b2    = (const float*)d_in[4];
    const float* W3    = (const float*)d_in[5];
    const float* b3    = (const float*)d_in[6];
    float* out = (float*)d_out;

    __bf16* w1bf = (__bf16*)d_ws;              // 400*32 bf16
    __bf16* w2bf = w1bf + 400 * K1P;           // 304*416 bf16

    const int total = 400 * K1P + N2P * K2P;   // 139264 elems (~272 KB in ws)
    prep_kernel<<<(total + 255) / 256, 256, 0, stream>>>(W1, W2, w1bf, w2bf);

    int B = in_sizes[0] / 17;                  // 65536
    actor_kernel<<<B / 64, 256, 0, stream>>>(state, w1bf, b1, w2bf, b2, W3, b3, out);
}

// Round 2
// 77.335 us; speedup vs baseline: 1.1342x; 1.1342x over previous
//
#include <hip/hip_runtime.h>
#include <hip/hip_bf16.h>

typedef __bf16 bf16x8 __attribute__((ext_vector_type(8)));
typedef float  f32x4  __attribute__((ext_vector_type(4)));

#define UBV    35.0f
#define SUMC   150.0f
#define SLOPE  0.2f

// Geometry: B=65536, S=17, H1=400, H2=300, A=5
// W1 staged as [400][32] bf16.  W2 staged as [320][424] bf16 (N2 padded 300->320,
// K2 padded 400->424-col rows; row stride 848B = 212 dw = 20 mod 32 -> 2-way = free).
#define K1P   32
#define W2S   424
#define W2SB  848
#define N2P   320
#define PAIRB 27136          // 32 rows * 848B per N-tile pair
#define BUFB  28672          // 7 chunks * 4096B  (staging granularity)
#define H1S   424            // s_h1 row stride (2-way = free)

__device__ __forceinline__ float lrelu(float x) { return x > 0.f ? x : SLOPE * x; }

__device__ __forceinline__ void async16(void* lds_uniform, const void* gsrc) {
    __builtin_amdgcn_global_load_lds(
        (__attribute__((address_space(1))) void*)(gsrc),
        (__attribute__((address_space(3))) void*)(lds_uniform),
        16, 0, 0);
}

// copy 7*4096 = 28672B: LDS dest wave-uniform base, global src per-lane (m104 rule)
__device__ __forceinline__ void stage7(const char* gbase, char* lbase, int wv, int ln) {
    #pragma unroll
    for (int ch = 0; ch < 7; ++ch)
        async16(lbase + ch * 4096 + wv * 1024,
                gbase + ch * 4096 + wv * 1024 + ln * 16);
}

__global__ void prep_kernel(const float* __restrict__ W1,
                            const float* __restrict__ W2,
                            __bf16* __restrict__ w1bf,   // [400][32]
                            __bf16* __restrict__ w2bf)   // [320][424]
{
    int idx = blockIdx.x * blockDim.x + threadIdx.x;
    const int total1 = 400 * K1P;           // 12800
    const int total2 = N2P * W2S;           // 135680
    if (idx < total1) {
        int j = idx >> 5, k = idx & 31;
        w1bf[idx] = (k < 17) ? (__bf16)W1[j * 17 + k] : (__bf16)0.f;
    } else if (idx < total1 + total2) {
        int i2 = idx - total1;
        int n = i2 / W2S, k = i2 - n * W2S;
        w2bf[i2] = (n < 300 && k < 400) ? (__bf16)W2[n * 400 + k] : (__bf16)0.f;
    }
}

__global__ __launch_bounds__(256, 1)
void actor_kernel(const float* __restrict__ state,
                  const __bf16* __restrict__ w1bf,
                  const float* __restrict__ b1,
                  const __bf16* __restrict__ w2bf,
                  const float* __restrict__ b2,
                  const float* __restrict__ W3,
                  const float* __restrict__ b3,
                  float* __restrict__ out)
{
    __shared__ __align__(16) __bf16 s_h1[64][H1S];   // 54,272B
    __shared__ __align__(16) char   s_w2[2][BUFB];   // 57,344B (also stages W1)
    __shared__ float s_state[64][17];                // 4,352B
    __shared__ float s_w3[5][N2P];                   // 6,400B
    __shared__ float s_b1[400];
    __shared__ float s_b2[N2P];
    __shared__ float s_b3[8];

    const int tid  = threadIdx.x;
    const int wv   = tid >> 6;
    const int ln   = tid & 63;
    const int g    = ln >> 4;
    const int c16  = ln & 15;
    const int brow = blockIdx.x * 64;
    const int mrow = wv * 16;

    // ---- stage W1 (25,600B -> 7 chunks, fits buf pair region) + state + consts ----
    stage7((const char*)w1bf, &s_w2[0][0], wv, ln);
    {
        const float* src = state + brow * 17;        // 64*17 floats contiguous
        float* dst = &s_state[0][0];
        for (int i = tid; i < 64 * 17; i += 256) dst[i] = src[i];
    }
    for (int i = tid; i < 400; i += 256) s_b1[i] = b1[i];
    for (int i = tid; i < N2P; i += 256) s_b2[i] = (i < 300) ? b2[i] : 0.f;
    for (int i = tid; i < 5 * N2P; i += 256) {
        int o = i / N2P, c = i - o * N2P;
        s_w3[o][c] = (c < 300) ? W3[o * 300 + c] : 0.f;
    }
    if (tid < 5) s_b3[tid] = b3[tid];
    for (int i = tid; i < 64 * 24; i += 256) {       // zero h1 pad cols 400..423
        int r = i / 24, c = 400 + (i - r * 24);
        s_h1[r][c] = (__bf16)0.f;
    }
    __syncthreads();

    // ---- Phase A: layer 1, W1 B-frags from LDS ----
    bf16x8 afrag;
    #pragma unroll
    for (int j = 0; j < 8; ++j) {
        int k = g * 8 + j;
        afrag[j] = (__bf16)((k < 17) ? s_state[mrow + c16][k] : 0.f);
    }
    const __bf16* w1l = (const __bf16*)&s_w2[0][0];
    #pragma unroll
    for (int nt = 0; nt < 25; ++nt) {
        bf16x8 bfrag = *(const bf16x8*)(w1l + (nt * 16 + c16) * K1P + g * 8);
        f32x4 acc = {0.f, 0.f, 0.f, 0.f};
        acc = __builtin_amdgcn_mfma_f32_16x16x32_bf16(afrag, bfrag, acc, 0, 0, 0);
        int jc = nt * 16 + c16;
        float bias = s_b1[jc];
        #pragma unroll
        for (int r = 0; r < 4; ++r)
            s_h1[mrow + g * 4 + r][jc] = (__bf16)lrelu(acc[r] + bias);
    }
    __syncthreads();                                  // w1 region free; h1 complete

    // ---- Phase B: stage pair 0, hoist A-frags ----
    stage7((const char*)w2bf, &s_w2[0][0], wv, ln);

    bf16x8 af[13];
    #pragma unroll
    for (int kt = 0; kt < 13; ++kt)
        af[kt] = *(const bf16x8*)(&s_h1[mrow + c16][kt * 32 + g * 8]);

    float part[5][4];
    #pragma unroll
    for (int o = 0; o < 5; ++o)
        #pragma unroll
        for (int r = 0; r < 4; ++r) part[o][r] = 0.f;

    __syncthreads();                                  // pair0 staged (vmcnt drained)

    // ---- 10 N-tile pairs, double-buffered; 2 independent MFMA chains ----
    for (int p = 0; p < 10; ++p) {
        if (p < 9)
            stage7((const char*)w2bf + (p + 1) * PAIRB, &s_w2[(p + 1) & 1][0], wv, ln);
        const char* buf = &s_w2[p & 1][0];
        const __bf16* r0 = (const __bf16*)(buf + c16 * W2SB);
        const __bf16* r1 = (const __bf16*)(buf + (16 + c16) * W2SB);
        f32x4 a0 = {0.f, 0.f, 0.f, 0.f}, a1 = {0.f, 0.f, 0.f, 0.f};
        #pragma unroll
        for (int kt = 0; kt < 13; ++kt) {
            bf16x8 bf0 = *(const bf16x8*)(r0 + kt * 32 + g * 8);
            bf16x8 bf1 = *(const bf16x8*)(r1 + kt * 32 + g * 8);
            a0 = __builtin_amdgcn_mfma_f32_16x16x32_bf16(af[kt], bf0, a0, 0, 0, 0);
            a1 = __builtin_amdgcn_mfma_f32_16x16x32_bf16(af[kt], bf1, a1, 0, 0, 0);
        }
        int cc0 = p * 32 + c16, cc1 = cc0 + 16;
        float bias0 = s_b2[cc0], bias1 = s_b2[cc1];
        #pragma unroll
        for (int r = 0; r < 4; ++r) {
            float h0 = lrelu(a0[r] + bias0);
            float h1v = lrelu(a1[r] + bias1);
            #pragma unroll
            for (int o = 0; o < 5; ++o)
                part[o][r] += h0 * s_w3[o][cc0] + h1v * s_w3[o][cc1];
        }
        __syncthreads();
    }

    // ---- reduce across the 16 lanes sharing g ----
    #pragma unroll
    for (int o = 0; o < 5; ++o)
        #pragma unroll
        for (int r = 0; r < 4; ++r) {
            float x = part[o][r];
            x += __shfl_xor(x, 1);
            x += __shfl_xor(x, 2);
            x += __shfl_xor(x, 4);
            x += __shfl_xor(x, 8);
            part[o][r] = x;
        }

    // ---- QP projection: exact piecewise-linear solve ----
    if (c16 < 4) {
        float v[5];
        #pragma unroll
        for (int o = 0; o < 5; ++o) {
            float x = (c16 == 0) ? part[o][0] :
                      (c16 == 1) ? part[o][1] :
                      (c16 == 2) ? part[o][2] : part[o][3];
            x = lrelu(x + s_b3[o]);
            v[o] = -x;
        }
        float bp[10];
        #pragma unroll
        for (int i = 0; i < 5; ++i) { bp[i] = v[i]; bp[i + 5] = v[i] - UBV; }
        float blo = -1e30f, glo = 0.f;
        #pragma unroll
        for (int j = 0; j < 10; ++j) {
            float b = bp[j];
            float gsum = 0.f;
            #pragma unroll
            for (int i = 0; i < 5; ++i) {
                float z = v[i] - b;
                z = fminf(fmaxf(z, 0.f), UBV);
                gsum += z;
            }
            if (gsum >= SUMC && b > blo) { blo = b; glo = gsum; }
        }
        float mid_unused = 0.f; (void)mid_unused;
        float bhi = 1e30f;
        #pragma unroll
        for (int j = 0; j < 10; ++j) {
            float b = bp[j];
            if (b > blo && b < bhi) bhi = b;
        }
        float mid = 0.5f * (blo + bhi);
        int nfree = 0;
        #pragma unroll
        for (int i = 0; i < 5; ++i)
            nfree += (v[i] > mid && v[i] < mid + UBV) ? 1 : 0;
        float nu = (nfree > 0) ? blo + (glo - SUMC) / (float)nfree : blo;

        int row = brow + mrow + g * 4 + c16;
        #pragma unroll
        for (int o = 0; o < 5; ++o) {
            float z = v[o] - nu;
            z = fminf(fmaxf(z, 0.f), UBV);
            out[row * 5 + o] = z;
        }
    }
}

extern "C" void kernel_launch(void* const* d_in, const int* in_sizes, int n_in,
                              void* d_out, int out_size, void* d_ws, size_t ws_size,
                              hipStream_t stream) {
    const float* state = (const float*)d_in[0];
    const float* W1    = (const float*)d_in[1];
    const float* b1    = (const float*)d_in[2];
    const float* W2    = (const float*)d_in[3];
    const float* b2    = (const float*)d_in[4];
    const float* W3    = (const float*)d_in[5];
    const float* b3    = (const float*)d_in[6];
    float* out = (float*)d_out;

    __bf16* w1bf = (__bf16*)d_ws;                  // 400*32  = 25,600B
    __bf16* w2bf = w1bf + 400 * K1P;               // 320*424 = 271,360B (+1,536B overread pad)

    const int total = 400 * K1P + N2P * W2S;       // 148,480 elems
    prep_kernel<<<(total + 255) / 256, 256, 0, stream>>>(W1, W2, w1bf, w2bf);

    int B = in_sizes[0] / 17;                      // 65536
    actor_kernel<<<B / 64, 256, 0, stream>>>(state, w1bf, b1, w2bf, b2, W3, b3, out);
}